// Round 14
// baseline (3670.305 us; speedup 1.0000x reference)
//
#include <hip/hip_runtime.h>

typedef _Float16 half8 __attribute__((ext_vector_type(8)));
typedef _Float16 half4_ __attribute__((ext_vector_type(4)));
typedef float f32x4 __attribute__((ext_vector_type(4)));

namespace {
constexpr int kB = 2048;
constexpr int kT = 72;
constexpr int kI = 200;
constexpr int kH = 200;
constexpr int kO = 53;
constexpr int kG = 600;      // 3*kH
constexpr int BT = 8;        // batch rows per WG -> 256 WGs -> all 256 CUs
constexpr int NWG = kB / BT; // 256
constexpr int KS = 7;        // K slices of 32 covering 224 (200 padded)
constexpr int MT2 = 39;      // 13 jblocks x 3 gates (r,z,n triplet tiles)
constexpr int PERM2 = MT2 * KS * 64;

// ws layout (float offsets). Kernel order: transpose2 -> input -> frags -> main.
constexpr int XW1    = 0;          // [2048][600] emb@Wih1^T + bih1
constexpr int WIH1T  = 1228800;    // prep_input only
constexpr int FCINT  = 1348800;    // prep_input only
constexpr int F0     = 1228800;    // triplet fp16 A-frags (overwrites WIH1T after prep_input)
constexpr int FSZ2   = 69888;      // floats per frag matrix
constexpr int FHEAD  = F0 + 5 * FSZ2;

// output offsets (floats)
constexpr int OH1 = kB * kT * kO;  // 7815168
constexpr int OH2 = OH1 + kB * kH;
constexpr int OH3 = OH2 + kB * kH;
}

__device__ __forceinline__ float sig_(float x) { return 1.0f / (1.0f + __expf(-x)); }
__device__ __forceinline__ float tanh_(float x) {
    return 1.0f - 2.0f / (__expf(2.0f * x) + 1.0f);
}

// barrier draining LDS only; in-flight global weight loads survive (validated R6/R9/R12/R13).
__device__ __forceinline__ void barx() {
    asm volatile("s_waitcnt lgkmcnt(0)\n\ts_barrier" ::: "memory");
}

// ---------------- prep kernels (identical to validated R6) ----------------

__global__ __launch_bounds__(256) void prep_transpose2(
    const float* __restrict__ Wih1, const float* __restrict__ fciW,
    float* __restrict__ ws) {
    int idx = blockIdx.x * 256 + threadIdx.x;
    if (idx < 120000) {
        int k = idx / kG, c = idx - k * kG;
        ws[WIH1T + idx] = Wih1[c * kI + k];
    } else {
        int i = idx - 120000;
        if (i < 40000) {
            int k = i / kH, h = i - k * kH;
            ws[FCINT + i] = fciW[h * kI + k];
        }
    }
}

__global__ __launch_bounds__(256) void prep_input(
    const float* __restrict__ enc,
    const float* __restrict__ bn_g, const float* __restrict__ bn_b,
    const float* __restrict__ bn_m, const float* __restrict__ bn_v,
    const float* __restrict__ fcib, const float* __restrict__ bih1,
    float* ws) {
    __shared__ float xh[kI];
    __shared__ float emb[kH];
    const int b = blockIdx.x, tid = threadIdx.x;
    const float* fcInT = ws + FCINT;
    const float* Wih1T = ws + WIH1T;
    if (tid < kI) {
        float x = enc[b * kI + tid];
        xh[tid] = (x - bn_m[tid]) * rsqrtf(bn_v[tid] + 1e-5f) * bn_g[tid] + bn_b[tid];
    }
    __syncthreads();
    if (tid < kH) {
        float s = fcib[tid];
        for (int k = 0; k < kI; ++k) s = fmaf(xh[k], fcInT[k * kH + tid], s);
        emb[tid] = fmaxf(s, 0.0f);
    }
    __syncthreads();
    for (int c = tid; c < kG; c += 256) {
        float s = bih1[c];
        for (int k = 0; k < kH; ++k) s = fmaf(emb[k], Wih1T[k * kG + c], s);
        ws[XW1 + b * kG + c] = s;
    }
}

// triplet tile order: mt = 3*jb + g; frag elem j -> W[g*200 + jb*16 + (lane&15)][ks*32+(lane>>4)*8+j]
__global__ __launch_bounds__(256) void prep_frags(
    const float* __restrict__ Whh1, const float* __restrict__ Wih2,
    const float* __restrict__ Whh2, const float* __restrict__ Wih3,
    const float* __restrict__ Whh3, const float* __restrict__ fcoW,
    float* __restrict__ ws) {
    int idx = blockIdx.x * 256 + threadIdx.x;
    if (idx < 5 * PERM2) {
        int m = idx / PERM2, rem = idx - m * PERM2;
        const float* src;
        switch (m) {
            case 0: src = Whh1; break;
            case 1: src = Wih2; break;
            case 2: src = Whh2; break;
            case 3: src = Wih3; break;
            default: src = Whh3; break;
        }
        int lane = rem & 63;
        int tmp = rem >> 6;
        int ks = tmp % KS;
        int mt = tmp / KS;
        int b = mt / 3, g = mt - 3 * b;
        int rt = b * 16 + (lane & 15);
        int row = g * kH + rt;
        int k0 = ks * 32 + (lane >> 4) * 8;
        half8 v;
        #pragma unroll
        for (int j = 0; j < 8; ++j) {
            int k = k0 + j;
            v[j] = (_Float16)((rt < kH && k < kH) ? src[row * kH + k] : 0.0f);
        }
        *(half8*)((_Float16*)ws + 2LL * (F0 + m * FSZ2) + (long long)rem * 8) = v;
    } else {
        int rem = idx - 5 * PERM2;
        if (rem >= 4 * KS * 64) return;
        int lane = rem & 63;
        int tmp = rem >> 6;
        int ks = tmp % KS;
        int mt = tmp / KS;
        int row = mt * 16 + (lane & 15);
        int k0 = ks * 32 + (lane >> 4) * 8;
        half8 v;
        #pragma unroll
        for (int j = 0; j < 8; ++j) {
            int k = k0 + j;
            v[j] = (_Float16)((row < kO && k < kH) ? fcoW[row * kH + k] : 0.0f);
        }
        *(half8*)((_Float16*)ws + 2LL * FHEAD + (long long)rem * 8) = v;
    }
}

#define MFMA16(a, b, c) __builtin_amdgcn_mfma_f32_16x16x32_f16((a), (b), (c), 0, 0, 0)

// fused L2/L3 phase: x-proj + h-proj matmuls + in-register GRU update (R6, validated)
__device__ __forceinline__ void layer23(
    const half8* __restrict__ px, const half8* __restrict__ ph,
    const _Float16* __restrict__ fx, const _Float16* __restrict__ fh,
    const float* __restrict__ bsb,   // 4 consecutive [208] arrays: r, z, xn, hn
    float* hreg, _Float16* __restrict__ fbdst, int fboff,
    int j0, int ln, int lr, bool lo, half8 z8) {
    f32x4 ar = {0,0,0,0}, az = {0,0,0,0}, anx = {0,0,0,0}, anh = {0,0,0,0};
    #pragma unroll
    for (int ks = 0; ks < KS; ++ks) {
        bool full = (ks < KS - 1) || lo;   // ks=6 trim (bit-exact: pad weights are 0)
        half8 xr = full ? px[ks * 64] : z8;
        half8 xz = full ? px[KS * 64 + ks * 64] : z8;
        half8 xn = full ? px[2 * KS * 64 + ks * 64] : z8;
        half8 hr = full ? ph[ks * 64] : z8;
        half8 hz = full ? ph[KS * 64 + ks * 64] : z8;
        half8 hn = full ? ph[2 * KS * 64 + ks * 64] : z8;
        half8 bx = *(const half8*)(fx + ((ks * 64 + ln) << 3));
        half8 bh = *(const half8*)(fh + ((ks * 64 + ln) << 3));
        ar  = MFMA16(xr, bx, ar);  ar  = MFMA16(hr, bh, ar);
        az  = MFMA16(xz, bx, az);  az  = MFMA16(hz, bh, az);
        anx = MFMA16(xn, bx, anx); anh = MFMA16(hn, bh, anh);
    }
    half4_ hv;
    #pragma unroll
    for (int rg = 0; rg < 4; ++rg) {
        int j = j0 + rg;
        float r  = sig_(ar[rg] + bsb[j]);
        float z  = sig_(az[rg] + bsb[208 + j]);
        float nn = tanh_(anx[rg] + bsb[2 * 208 + j] + r * (anh[rg] + bsb[3 * 208 + j]));
        hreg[rg] = (1.0f - z) * nn + z * hreg[rg];
        hv[rg] = (_Float16)hreg[rg];
    }
    if (lr < BT) *(half4_*)(&fbdst[fboff]) = hv;   // BT=8: cols 8-15 stay zero
}

// head: sigmoid(h3 @ fc_out^T + b) for timestep tt (MFMA wave-uniform; stores guarded)
__device__ __forceinline__ void head_mm(
    const half8* __restrict__ WFhd, const _Float16* __restrict__ fr,
    const float* __restrict__ hb, float* __restrict__ out,
    int hw, int tt, int b0, int ln, int lq, int lr) {
    const half8* pw0 = WFhd + hw * (KS * 64) + ln;
    const half8* pw1 = WFhd + 3 * (KS * 64) + ln;   // tile 3 done by hw==0 (wave-uniform)
    f32x4 a0 = {0,0,0,0}, a1 = {0,0,0,0};
    #pragma unroll
    for (int ks = 0; ks < KS; ++ks) {
        half8 bfv = *(const half8*)(fr + ((ks * 64 + ln) << 3));
        a0 = MFMA16(pw0[ks * 64], bfv, a0);
        if (hw == 0) a1 = MFMA16(pw1[ks * 64], bfv, a1);
    }
    if (lr < BT) {
        int obase = (b0 + lr) * (kT * kO) + tt * kO;
        #pragma unroll
        for (int rg = 0; rg < 4; ++rg) {
            int o = hw * 16 + lq * 4 + rg;
            if (o < kO) out[obase + o] = sig_(a0[rg] + hb[o]);
        }
        if (hw == 0) {
            #pragma unroll
            for (int rg = 0; rg < 4; ++rg) {
                int o = 48 + lq * 4 + rg;
                if (o < kO) out[obase + o] = sig_(a1[rg] + hb[o]);
            }
        }
    }
}

// ---------------- main persistent GRU kernel ----------------
// 256 WGs x 512 threads (8 waves, 1 WG/CU, (512,1) -> 128-VGPR budget, R12-proven).
// R6 gate-triplet structure at BT=8: waves 0-4 own jblocks {w, w+8}; waves 5-7
// own jblock {w} + head tiles. GRU update in registers (C-lane owns (j,n));
// 3 lgkm-only barriers/step; fb ping-pong parity; fb cols 8-15 & pads zero.
__global__ __launch_bounds__(512, 1) void gru_main(
    const float* __restrict__ ws,
    const float* __restrict__ h1in, const float* __restrict__ h2in,
    const float* __restrict__ h3in,
    const float* __restrict__ bhh1,
    const float* __restrict__ bih2, const float* __restrict__ bhh2,
    const float* __restrict__ bih3, const float* __restrict__ bhh3,
    const float* __restrict__ fcob,
    float* __restrict__ out) {
    __shared__ float xw1f[3 * 208 * 17];                       // 42432 B
    __shared__ float bs[9 * 208];                              // 7488 B
    __shared__ __align__(16) _Float16 fb[3][2][KS * 64 * 8];   // 43008 B ping-pong
    __shared__ float hb[64];
    // total ~93 KB -> exactly 1 WG/CU

    const int tid = threadIdx.x, wv = tid >> 6, ln = tid & 63;
    const int lq = ln >> 4, lr = ln & 15;
    const int b0 = blockIdx.x * BT;
    const bool lo = (ln < 16);
    half8 z8;
    #pragma unroll
    for (int j = 0; j < 8; ++j) z8[j] = (_Float16)0.0f;

    const int njb = (wv < 5) ? 2 : 1;       // waves 0-4: jblocks {wv, wv+8}; 5-7: {wv}
    const int jb0 = wv, jb1 = wv + 8;
    const int j0a = jb0 * 16 + lq * 4;
    const int j0b = jb1 * 16 + lq * 4;
    auto fboff_of = [&](int j0) {
        int ks6 = j0 >> 5, rr = j0 & 31;
        return (((ks6 << 6) + ((rr >> 3) << 4) + lr) << 3) + (rr & 7);
    };
    const int fba = fboff_of(j0a), fbb = fboff_of(j0b);

    // ---- zero ALL fb (both parities): batch-cols 8-15 + K-pads stay exact zeros
    {
        float4* f = (float4*)&fb[0][0][0];
        const float4 z4 = {0.f, 0.f, 0.f, 0.f};
        for (int i = tid; i < 3 * 2 * KS * 64 * 8 * 2 / 16; i += 512) f[i] = z4;
    }
    // ---- stage xw1 (+ bih1 folded; add bhh1 for r,z); n>=8 zero (no OOB on last WG)
    for (int i = tid; i < 3 * 208 * 16; i += 512) {
        int g = i / 3328, rem = i - g * 3328, j = rem >> 4, n = rem & 15;
        float v = 0.0f;
        if (j < kH && n < BT) {
            v = ws[XW1 + (b0 + n) * kG + g * kH + j];
            if (g < 2) v += bhh1[g * kH + j];
        }
        xw1f[g * 3536 + j * 17 + n] = v;
    }
    // ---- biases (208-padded): 0=bhh1_n 1=b2r 2=b2z 3=b2xn 4=b2hn 5=b3r 6=b3z 7=b3xn 8=b3hn
    for (int i = tid; i < 9 * 208; i += 512) {
        int c = i / 208, j = i - c * 208;
        float v = 0.0f;
        if (j < kH) {
            switch (c) {
                case 0: v = bhh1[2 * kH + j]; break;
                case 1: v = bih2[j] + bhh2[j]; break;
                case 2: v = bih2[kH + j] + bhh2[kH + j]; break;
                case 3: v = bih2[2 * kH + j]; break;
                case 4: v = bhh2[2 * kH + j]; break;
                case 5: v = bih3[j] + bhh3[j]; break;
                case 6: v = bih3[kH + j] + bhh3[kH + j]; break;
                case 7: v = bih3[2 * kH + j]; break;
                default: v = bhh3[2 * kH + j]; break;
            }
        }
        bs[i] = v;
    }
    if (tid < 64) hb[tid] = (tid < kO) ? fcob[tid] : 0.0f;
    __syncthreads();   // fb zeroing complete before shadow writes

    // ---- h states -> registers; parity-0 fb shadows
    float h1r[2][4], h2r[2][4], h3r[2][4];
    #pragma unroll
    for (int u = 0; u < 2; ++u) {
        const int j0u = (u == 0) ? j0a : j0b;
        const bool act = (u < njb);
        half4_ v1, v2, v3;
        #pragma unroll
        for (int rg = 0; rg < 4; ++rg) {
            int j = j0u + rg;
            bool val = act && (j < kH) && (lr < BT);
            float a1 = val ? h1in[(b0 + lr) * kH + j] : 0.0f;
            float a2 = val ? h2in[(b0 + lr) * kH + j] : 0.0f;
            float a3 = val ? h3in[(b0 + lr) * kH + j] : 0.0f;
            h1r[u][rg] = a1; h2r[u][rg] = a2; h3r[u][rg] = a3;
            v1[rg] = (_Float16)a1; v2[rg] = (_Float16)a2; v3[rg] = (_Float16)a3;
        }
        if (act && lr < BT) {
            int off = (u == 0) ? fba : fbb;
            *(half4_*)(&fb[0][0][off]) = v1;
            *(half4_*)(&fb[1][0][off]) = v2;
            *(half4_*)(&fb[2][0][off]) = v3;
        }
    }
    __syncthreads();

    const half8* WF1  = (const half8*)(ws + F0);
    const half8* WF2x = (const half8*)(ws + F0 + 1 * FSZ2);
    const half8* WF2h = (const half8*)(ws + F0 + 2 * FSZ2);
    const half8* WF3x = (const half8*)(ws + F0 + 3 * FSZ2);
    const half8* WF3h = (const half8*)(ws + F0 + 4 * FSZ2);
    const half8* WFhd = (const half8*)(ws + FHEAD);

    for (int t = 0; t < kT; ++t) {
        const int p = t & 1, q = p ^ 1;
        // ---------- phase L1 (+ head(t-1) on waves 5-7) ----------
        {
            const _Float16* fr = fb[0][p];
            #pragma unroll
            for (int u = 0; u < 2; ++u) {
                if (u < njb) {
                    const int jb = (u == 0) ? jb0 : jb1;
                    const int j0u = (u == 0) ? j0a : j0b;
                    const half8* pw = WF1 + 3 * jb * (KS * 64) + ln;
                    f32x4 ra = {0,0,0,0}, za = {0,0,0,0}, na = {0,0,0,0};
                    #pragma unroll
                    for (int ks = 0; ks < KS; ++ks) {
                        bool full = (ks < KS - 1) || lo;
                        half8 wr = full ? pw[ks * 64] : z8;
                        half8 wz = full ? pw[KS * 64 + ks * 64] : z8;
                        half8 wn = full ? pw[2 * KS * 64 + ks * 64] : z8;
                        half8 bfv = *(const half8*)(fr + ((ks * 64 + ln) << 3));
                        ra = MFMA16(wr, bfv, ra);
                        za = MFMA16(wz, bfv, za);
                        na = MFMA16(wn, bfv, na);
                    }
                    half4_ hv;
                    float* hp = (u == 0) ? h1r[0] : h1r[1];
                    #pragma unroll
                    for (int rg = 0; rg < 4; ++rg) {
                        int j = j0u + rg;
                        float r  = sig_(xw1f[j * 17 + lr] + ra[rg]);
                        float z  = sig_(xw1f[3536 + j * 17 + lr] + za[rg]);
                        float nn = tanh_(xw1f[2 * 3536 + j * 17 + lr] + r * (na[rg] + bs[j]));
                        hp[rg] = (1.0f - z) * nn + z * hp[rg];
                        hv[rg] = (_Float16)hp[rg];
                    }
                    if (lr < BT) *(half4_*)(&fb[0][q][(u == 0) ? fba : fbb]) = hv;
                }
            }
            if (wv >= 5 && t > 0)
                head_mm(WFhd, fb[2][p], hb, out, wv - 5, t - 1, b0, ln, lq, lr);
        }
        barx();
        // ---------- phase L2 ----------
        #pragma unroll
        for (int u = 0; u < 2; ++u) {
            if (u < njb) {
                const int jb = (u == 0) ? jb0 : jb1;
                layer23(WF2x + 3 * jb * (KS * 64) + ln, WF2h + 3 * jb * (KS * 64) + ln,
                        fb[0][q], fb[1][p], &bs[1 * 208],
                        (u == 0) ? h2r[0] : h2r[1], fb[1][q], (u == 0) ? fba : fbb,
                        (u == 0) ? j0a : j0b, ln, lr, lo, z8);
            }
        }
        barx();
        // ---------- phase L3 ----------
        #pragma unroll
        for (int u = 0; u < 2; ++u) {
            if (u < njb) {
                const int jb = (u == 0) ? jb0 : jb1;
                layer23(WF3x + 3 * jb * (KS * 64) + ln, WF3h + 3 * jb * (KS * 64) + ln,
                        fb[1][q], fb[2][p], &bs[5 * 208],
                        (u == 0) ? h3r[0] : h3r[1], fb[2][q], (u == 0) ? fba : fbb,
                        (u == 0) ? j0a : j0b, ln, lr, lo, z8);
            }
        }
        barx();
    }

    // ---------- final head (t = kT-1; h3 is in fb[2][kT&1]) + final h states ----------
    if (wv >= 5)
        head_mm(WFhd, fb[2][kT & 1], hb, out, wv - 5, kT - 1, b0, ln, lq, lr);
    #pragma unroll
    for (int u = 0; u < 2; ++u) {
        if (u < njb && lr < BT) {
            const int j0u = (u == 0) ? j0a : j0b;
            #pragma unroll
            for (int rg = 0; rg < 4; ++rg) {
                int j = j0u + rg;
                if (j < kH) {
                    out[OH1 + (b0 + lr) * kH + j] = h1r[u][rg];
                    out[OH2 + (b0 + lr) * kH + j] = h2r[u][rg];
                    out[OH3 + (b0 + lr) * kH + j] = h3r[u][rg];
                }
            }
        }
    }
}

extern "C" void kernel_launch(void* const* d_in, const int* in_sizes, int n_in,
                              void* d_out, int out_size, void* d_ws, size_t ws_size,
                              hipStream_t stream) {
    (void)in_sizes; (void)n_in; (void)out_size; (void)ws_size;
    const float* enc  = (const float*)d_in[0];
    const float* h1in = (const float*)d_in[1];
    const float* h2in = (const float*)d_in[2];
    const float* h3in = (const float*)d_in[3];
    const float* bn_g = (const float*)d_in[4];
    const float* bn_b = (const float*)d_in[5];
    const float* bn_m = (const float*)d_in[6];
    const float* bn_v = (const float*)d_in[7];
    const float* fciW = (const float*)d_in[8];
    const float* fcib = (const float*)d_in[9];
    const float* Wih1 = (const float*)d_in[10];
    const float* Whh1 = (const float*)d_in[11];
    const float* bih1 = (const float*)d_in[12];
    const float* bhh1 = (const float*)d_in[13];
    const float* Wih2 = (const float*)d_in[14];
    const float* Whh2 = (const float*)d_in[15];
    const float* bih2 = (const float*)d_in[16];
    const float* bhh2 = (const float*)d_in[17];
    const float* Wih3 = (const float*)d_in[18];
    const float* Whh3 = (const float*)d_in[19];
    const float* bih3 = (const float*)d_in[20];
    const float* bhh3 = (const float*)d_in[21];
    const float* fcoW = (const float*)d_in[22];
    const float* fcob = (const float*)d_in[23];
    float* ws  = (float*)d_ws;
    float* out = (float*)d_out;

    // order matters: prep_input consumes WIH1T/FCINT before prep_frags overwrites them
    hipLaunchKernelGGL(prep_transpose2, dim3(625), dim3(256), 0, stream, Wih1, fciW, ws);
    hipLaunchKernelGGL(prep_input, dim3(kB), dim3(256), 0, stream,
                       enc, bn_g, bn_b, bn_m, bn_v, fcib, bih1, ws);
    hipLaunchKernelGGL(prep_frags, dim3((5 * PERM2 + 4 * KS * 64 + 255) / 256), dim3(256), 0, stream,
                       Whh1, Wih2, Whh2, Wih3, Whh3, fcoW, ws);
    hipLaunchKernelGGL(gru_main, dim3(NWG), dim3(512), 0, stream,
                       ws, h1in, h2in, h3in, bhh1, bih2, bhh2, bih3, bhh3, fcob, out);
}

// Round 15
// 1102.008 us; speedup vs baseline: 3.3306x; 3.3306x over previous
//
#include <hip/hip_runtime.h>

typedef _Float16 half8 __attribute__((ext_vector_type(8)));
typedef float f32x4 __attribute__((ext_vector_type(4)));

namespace {
constexpr int kB = 2048;
constexpr int kT = 72;
constexpr int kI = 200;
constexpr int kH = 200;
constexpr int kO = 53;
constexpr int kG = 600;      // 3*kH
constexpr int BT = 8;        // batch rows per WG (8 -> 256 WGs -> all 256 CUs)
constexpr int NWG = kB / BT; // 256
constexpr int MT = 38;       // M tiles of 16 covering 608 (600 padded)
constexpr int KS = 7;        // K slices of 32 covering 224 (200 padded)
constexpr int GSTR = 18;     // LDS G col stride

// ws layout (float offsets) — identical to R4/R9/R13
constexpr int XW1    = 0;          // [2048][600] emb@Wih1^T + bih1
constexpr int WIH1T  = 1228800;    // [200][600] Wih1^T (prep only)
constexpr int FCINT  = 1348800;    // [200][200] fc_in_W^T (prep only)
constexpr int F0     = 1388800;    // fp16 A-frags: hh1, ih2, hh2, ih3, hh3
constexpr int FSZ    = 68096;      // floats per frag matrix
constexpr int FHEAD  = F0 + 5 * FSZ;
constexpr int PERM   = MT * KS * 64;

// output offsets (floats)
constexpr int OH1 = kB * kT * kO;  // 7815168
constexpr int OH2 = OH1 + kB * kH;
constexpr int OH3 = OH2 + kB * kH;
}

__device__ __forceinline__ float sig_(float x) { return 1.0f / (1.0f + __expf(-x)); }
__device__ __forceinline__ float tanh_(float x) {
    return 1.0f - 2.0f / (__expf(2.0f * x) + 1.0f);
}

// barrier draining LDS only; in-flight global weight loads survive (validated R6/R9/R12/R13).
__device__ __forceinline__ void barx() {
    asm volatile("s_waitcnt lgkmcnt(0)\n\ts_barrier" ::: "memory");
}

// fp16 fragment-order shadow write of h element (n, j); n < BT
__device__ __forceinline__ void store_fb(_Float16* fb, int n, int j, float v) {
    int ks = j >> 5, r = j & 31;
    fb[((ks << 6) + ((r >> 3) << 4) + n) * 8 + (r & 7)] = (_Float16)v;
}

// ---------------- prep kernels (identical to R4/R9/R13) ----------------

__global__ __launch_bounds__(256) void prep_transpose2(
    const float* __restrict__ Wih1, const float* __restrict__ fciW,
    float* __restrict__ ws) {
    int idx = blockIdx.x * 256 + threadIdx.x;
    if (idx < 120000) {
        int k = idx / kG, c = idx - k * kG;
        ws[WIH1T + idx] = Wih1[c * kI + k];
    } else {
        int i = idx - 120000;
        if (i < 40000) {
            int k = i / kH, h = i - k * kH;
            ws[FCINT + i] = fciW[h * kI + k];
        }
    }
}

__global__ __launch_bounds__(256) void prep_frags(
    const float* __restrict__ Whh1, const float* __restrict__ Wih2,
    const float* __restrict__ Whh2, const float* __restrict__ Wih3,
    const float* __restrict__ Whh3, const float* __restrict__ fcoW,
    float* __restrict__ ws) {
    int idx = blockIdx.x * 256 + threadIdx.x;
    const float* src; int R; long long dstHalf; int rem;
    if (idx < 5 * PERM) {
        int m = idx / PERM; rem = idx - m * PERM;
        switch (m) {
            case 0: src = Whh1; break;
            case 1: src = Wih2; break;
            case 2: src = Whh2; break;
            case 3: src = Wih3; break;
            default: src = Whh3; break;
        }
        R = kG; dstHalf = 2LL * (F0 + m * FSZ);
    } else {
        rem = idx - 5 * PERM;
        if (rem >= 4 * KS * 64) return;
        src = fcoW; R = kO; dstHalf = 2LL * FHEAD;
    }
    int lane = rem & 63;
    int tmp = rem >> 6;
    int ks = tmp % KS;
    int mt = tmp / KS;
    int row = mt * 16 + (lane & 15);
    int k0 = ks * 32 + (lane >> 4) * 8;
    half8 v;
    #pragma unroll
    for (int j = 0; j < 8; ++j) {
        int k = k0 + j;
        v[j] = (_Float16)((row < R && k < kH) ? src[row * kH + k] : 0.0f);
    }
    *(half8*)((_Float16*)ws + dstHalf + (long long)rem * 8) = v;
}

__global__ __launch_bounds__(256) void prep_input(
    const float* __restrict__ enc,
    const float* __restrict__ bn_g, const float* __restrict__ bn_b,
    const float* __restrict__ bn_m, const float* __restrict__ bn_v,
    const float* __restrict__ fcib, const float* __restrict__ bih1,
    float* ws) {
    __shared__ float xh[kI];
    __shared__ float emb[kH];
    const int b = blockIdx.x, tid = threadIdx.x;
    const float* fcInT = ws + FCINT;
    const float* Wih1T = ws + WIH1T;
    if (tid < kI) {
        float x = enc[b * kI + tid];
        xh[tid] = (x - bn_m[tid]) * rsqrtf(bn_v[tid] + 1e-5f) * bn_g[tid] + bn_b[tid];
    }
    __syncthreads();
    if (tid < kH) {
        float s = fcib[tid];
        for (int k = 0; k < kI; ++k) s = fmaf(xh[k], fcInT[k * kH + tid], s);
        emb[tid] = fmaxf(s, 0.0f);
    }
    __syncthreads();
    for (int c = tid; c < kG; c += 256) {
        float s = bih1[c];
        for (int k = 0; k < kH; ++k) s = fmaf(emb[k], Wih1T[k * kG + c], s);
        ws[XW1 + b * kG + c] = s;
    }
}

// ---------------- main persistent GRU kernel ----------------
// 256 WGs x 1024 threads (16 waves), one per CU. WG owns 8 batch rows.
// R13 skeleton (validated, 1110 us) + head-fold: the output head for step
// t-1 runs on waves 0-3 DURING phase M1 of step t (R6's validated overlap,
// transplanted); waves 4-15 cover all 38 M1 tiles (stride 12). Hazards:
// head reads fb3 (last write U3(t-1), barrier-separated); U3(t) rewrites
// fb3 five barriers later; M1 writes Gs which head never touches.
__global__ __launch_bounds__(1024, 4) void gru_main(
    const float* __restrict__ ws,
    const float* __restrict__ h1in, const float* __restrict__ h2in,
    const float* __restrict__ h3in,
    const float* __restrict__ bhh1,
    const float* __restrict__ bih2, const float* __restrict__ bhh2,
    const float* __restrict__ bih3, const float* __restrict__ bhh3,
    const float* __restrict__ fcob,
    float* __restrict__ out) {
    __shared__ float xwL[kG * BT];                         // 19200 B, [j][n]
    __shared__ __align__(16) _Float16 fb1[KS * 64 * 8];    // 7168 B each
    __shared__ __align__(16) _Float16 fb2[KS * 64 * 8];
    __shared__ __align__(16) _Float16 fb3[KS * 64 * 8];
    __shared__ __align__(16) _Float16 whdL[4 * KS * 64 * 8]; // 28672 B head frags
    __shared__ float Gs[608 * GSTR];                       // 43776 B
    __shared__ float Gns[208 * GSTR];                      // 14976 B
    __shared__ float bias[9 * kH];                         // 7200 B
    __shared__ float hb[64];

    const int tid = threadIdx.x, wv = tid >> 6, ln = tid & 63;
    const int lb = ln >> 4, lr = ln & 15;
    const int b0 = blockIdx.x * BT;
    const bool lo = (ln < 16);
    half8 z8;
    #pragma unroll
    for (int j = 0; j < 8; ++j) z8[j] = (_Float16)0.0f;

    // ---- zero ALL fb slots first (garbage batch-cols 8..15 + K-pad become 0)
    {
        float4* f1 = (float4*)fb1;
        float4* f2 = (float4*)fb2;
        float4* f3 = (float4*)fb3;
        const float4 z4 = {0.f, 0.f, 0.f, 0.f};
        for (int i = tid; i < KS * 64 * 8 * 2 / 16; i += 1024) {
            f1[i] = z4; f2[i] = z4; f3[i] = z4;
        }
    }
    // ---- head weights -> LDS (time-invariant, read every step)
    {
        const half8* src = (const half8*)(ws + FHEAD);
        for (int i = tid; i < 4 * KS * 64; i += 1024)
            *(half8*)(whdL + (long long)i * 8) = src[i];
    }
    // ---- stage xw1 (time-invariant) into LDS, folding bhh1 r/z biases
    for (int i = tid; i < kG * BT; i += 1024) {
        int n = i / kG, j = i - n * kG;
        float v = ws[XW1 + (b0 + n) * kG + j];
        if (j < 2 * kH) v += bhh1[j];
        xwL[j * BT + n] = v;
    }
    // ---- biases: [0]=b1n [1]=b2r [2]=b2z [3]=b2xn [4]=b2hn [5..8]=L3
    for (int i = tid; i < 9 * kH; i += 1024) {
        int c = i / kH, j = i - c * kH;
        float v;
        switch (c) {
            case 0:  v = bhh1[2 * kH + j]; break;
            case 1:  v = bih2[j] + bhh2[j]; break;
            case 2:  v = bih2[kH + j] + bhh2[kH + j]; break;
            case 3:  v = bih2[2 * kH + j]; break;
            case 4:  v = bhh2[2 * kH + j]; break;
            case 5:  v = bih3[j] + bhh3[j]; break;
            case 6:  v = bih3[kH + j] + bhh3[kH + j]; break;
            case 7:  v = bih3[2 * kH + j]; break;
            default: v = bhh3[2 * kH + j]; break;
        }
        bias[i] = v;
    }
    if (tid < 64) hb[tid] = (tid < kO) ? fcob[tid] : 0.0f;
    __syncthreads();   // fb zeroing complete before shadow writes

    // ---- h states -> registers + fp16 frag shadows (BT*kH = 1600 elems)
    float h1r[2], h2r[2], h3r[2];
    #pragma unroll
    for (int s = 0; s < 2; ++s) {
        int idx = tid + s * 1024;
        if (idx < BT * kH) {
            int n = idx & 7, j = idx >> 3;
            h1r[s] = h1in[(b0 + n) * kH + j];
            h2r[s] = h2in[(b0 + n) * kH + j];
            h3r[s] = h3in[(b0 + n) * kH + j];
            store_fb(fb1, n, j, h1r[s]);
            store_fb(fb2, n, j, h2r[s]);
            store_fb(fb3, n, j, h3r[s]);
        } else { h1r[s] = h2r[s] = h3r[s] = 0.0f; }
    }
    __syncthreads();

    const half8* WFhh1 = (const half8*)(ws + F0);
    const half8* WFih2 = (const half8*)(ws + F0 + FSZ);
    const half8* WFhh2 = (const half8*)(ws + F0 + 2 * FSZ);
    const half8* WFih3 = (const half8*)(ws + F0 + 3 * FSZ);
    const half8* WFhh3 = (const half8*)(ws + F0 + 4 * FSZ);

    for (int t = 0; t < kT; ++t) {
        // ---------- M1 (waves 4-15, all 38 tiles) || HEAD(t-1) (waves 0-3) ----------
        if (wv >= 4) {
            half8 bf[KS];
            #pragma unroll
            for (int ks = 0; ks < KS; ++ks)
                bf[ks] = *(const half8*)(fb1 + (ks * 64 + ln) * 8);
            for (int mt = wv - 4; mt < MT; mt += 12) {
                const half8* wp = WFhh1 + (mt * KS) * 64 + ln;
                f32x4 acc = {0.f, 0.f, 0.f, 0.f};
                #pragma unroll
                for (int ks = 0; ks < KS - 1; ++ks)
                    acc = __builtin_amdgcn_mfma_f32_16x16x32_f16(wp[ks * 64], bf[ks], acc, 0, 0, 0);
                half8 w6 = z8;
                if (lo) w6 = wp[(KS - 1) * 64];
                acc = __builtin_amdgcn_mfma_f32_16x16x32_f16(w6, bf[KS - 1], acc, 0, 0, 0);
                int row = mt * 16 + lb * 4;
                #pragma unroll
                for (int rg = 0; rg < 4; ++rg) Gs[(row + rg) * GSTR + lr] = acc[rg];
            }
        } else if (t > 0) {
            // head for step t-1: fb3 holds h3(t-1); whdL is LDS-resident
            f32x4 acc = {0.f, 0.f, 0.f, 0.f};
            #pragma unroll
            for (int ks = 0; ks < KS; ++ks) {
                half8 w = *(const half8*)(whdL + ((wv * KS + ks) * 64 + ln) * 8);
                half8 b = *(const half8*)(fb3 + (ks * 64 + ln) * 8);
                acc = __builtin_amdgcn_mfma_f32_16x16x32_f16(w, b, acc, 0, 0, 0);
            }
            if (lr < BT) {
                int o0 = wv * 16 + lb * 4;
                int obase = (b0 + lr) * (kT * kO) + (t - 1) * kO;
                #pragma unroll
                for (int rg = 0; rg < 4; ++rg) {
                    int o = o0 + rg;
                    if (o < kO) out[obase + o] = sig_(acc[rg] + hb[o]);
                }
            }
        }
        barx();
        // ---------- U1: update h1 ----------
        #pragma unroll
        for (int s = 0; s < 2; ++s) {
            int idx = tid + s * 1024;
            if (idx < BT * kH) {
                int n = idx & 7, j = idx >> 3;
                float r  = sig_(xwL[j * BT + n]            + Gs[j * GSTR + n]);
                float z  = sig_(xwL[(kH + j) * BT + n]     + Gs[(kH + j) * GSTR + n]);
                float nn = tanh_(xwL[(2 * kH + j) * BT + n] + r * (Gs[(2 * kH + j) * GSTR + n] + bias[j]));
                h1r[s] = (1.0f - z) * nn + z * h1r[s];
                store_fb(fb1, n, j, h1r[s]);
            }
        }
        barx();
        // ---------- M2: Wih2 x h1 + Whh2 x h2 ----------
        {
            half8 bx[KS], bh[KS];
            #pragma unroll
            for (int ks = 0; ks < KS; ++ks) {
                bx[ks] = *(const half8*)(fb1 + (ks * 64 + ln) * 8);
                bh[ks] = *(const half8*)(fb2 + (ks * 64 + ln) * 8);
            }
            for (int mt = wv; mt < MT; mt += 16) {
                const half8* wpx = WFih2 + (mt * KS) * 64 + ln;
                const half8* wph = WFhh2 + (mt * KS) * 64 + ln;
                f32x4 ax = {0.f, 0.f, 0.f, 0.f}, ah = {0.f, 0.f, 0.f, 0.f};
                #pragma unroll
                for (int ks = 0; ks < KS - 1; ++ks) {
                    ax = __builtin_amdgcn_mfma_f32_16x16x32_f16(wpx[ks * 64], bx[ks], ax, 0, 0, 0);
                    ah = __builtin_amdgcn_mfma_f32_16x16x32_f16(wph[ks * 64], bh[ks], ah, 0, 0, 0);
                }
                half8 wx6 = z8, wh6 = z8;
                if (lo) { wx6 = wpx[(KS - 1) * 64]; wh6 = wph[(KS - 1) * 64]; }
                ax = __builtin_amdgcn_mfma_f32_16x16x32_f16(wx6, bx[KS - 1], ax, 0, 0, 0);
                ah = __builtin_amdgcn_mfma_f32_16x16x32_f16(wh6, bh[KS - 1], ah, 0, 0, 0);
                int row = mt * 16 + lb * 4;
                if (mt < 25) {
                    #pragma unroll
                    for (int rg = 0; rg < 4; ++rg) Gs[(row + rg) * GSTR + lr] = ax[rg] + ah[rg];
                } else {
                    #pragma unroll
                    for (int rg = 0; rg < 4; ++rg) {
                        Gs[(row + rg) * GSTR + lr] = ax[rg];
                        Gns[(row - 400 + rg) * GSTR + lr] = ah[rg];
                    }
                }
            }
        }
        barx();
        // ---------- U2: update h2 ----------
        #pragma unroll
        for (int s = 0; s < 2; ++s) {
            int idx = tid + s * 1024;
            if (idx < BT * kH) {
                int n = idx & 7, j = idx >> 3;
                float r  = sig_(Gs[j * GSTR + n]            + bias[kH + j]);
                float z  = sig_(Gs[(kH + j) * GSTR + n]     + bias[2 * kH + j]);
                float nn = tanh_(Gs[(2 * kH + j) * GSTR + n] + bias[3 * kH + j]
                                 + r * (Gns[j * GSTR + n]   + bias[4 * kH + j]));
                h2r[s] = (1.0f - z) * nn + z * h2r[s];
                store_fb(fb2, n, j, h2r[s]);
            }
        }
        barx();
        // ---------- M3: Wih3 x h2 + Whh3 x h3 ----------
        {
            half8 bx[KS], bh[KS];
            #pragma unroll
            for (int ks = 0; ks < KS; ++ks) {
                bx[ks] = *(const half8*)(fb2 + (ks * 64 + ln) * 8);
                bh[ks] = *(const half8*)(fb3 + (ks * 64 + ln) * 8);
            }
            for (int mt = wv; mt < MT; mt += 16) {
                const half8* wpx = WFih3 + (mt * KS) * 64 + ln;
                const half8* wph = WFhh3 + (mt * KS) * 64 + ln;
                f32x4 ax = {0.f, 0.f, 0.f, 0.f}, ah = {0.f, 0.f, 0.f, 0.f};
                #pragma unroll
                for (int ks = 0; ks < KS - 1; ++ks) {
                    ax = __builtin_amdgcn_mfma_f32_16x16x32_f16(wpx[ks * 64], bx[ks], ax, 0, 0, 0);
                    ah = __builtin_amdgcn_mfma_f32_16x16x32_f16(wph[ks * 64], bh[ks], ah, 0, 0, 0);
                }
                half8 wx6 = z8, wh6 = z8;
                if (lo) { wx6 = wpx[(KS - 1) * 64]; wh6 = wph[(KS - 1) * 64]; }
                ax = __builtin_amdgcn_mfma_f32_16x16x32_f16(wx6, bx[KS - 1], ax, 0, 0, 0);
                ah = __builtin_amdgcn_mfma_f32_16x16x32_f16(wh6, bh[KS - 1], ah, 0, 0, 0);
                int row = mt * 16 + lb * 4;
                if (mt < 25) {
                    #pragma unroll
                    for (int rg = 0; rg < 4; ++rg) Gs[(row + rg) * GSTR + lr] = ax[rg] + ah[rg];
                } else {
                    #pragma unroll
                    for (int rg = 0; rg < 4; ++rg) {
                        Gs[(row + rg) * GSTR + lr] = ax[rg];
                        Gns[(row - 400 + rg) * GSTR + lr] = ah[rg];
                    }
                }
            }
        }
        barx();
        // ---------- U3: update h3 ----------
        #pragma unroll
        for (int s = 0; s < 2; ++s) {
            int idx = tid + s * 1024;
            if (idx < BT * kH) {
                int n = idx & 7, j = idx >> 3;
                float r  = sig_(Gs[j * GSTR + n]            + bias[5 * kH + j]);
                float z  = sig_(Gs[(kH + j) * GSTR + n]     + bias[6 * kH + j]);
                float nn = tanh_(Gs[(2 * kH + j) * GSTR + n] + bias[7 * kH + j]
                                 + r * (Gns[j * GSTR + n]   + bias[8 * kH + j]));
                h3r[s] = (1.0f - z) * nn + z * h3r[s];
                store_fb(fb3, n, j, h3r[s]);
            }
        }
        barx();
        // (head for this step runs during M1 of step t+1; final step handled below)
    }

    // ---------- final head (t = kT-1): fb3 holds h3(kT-1) ----------
    if (wv < 4) {
        f32x4 acc = {0.f, 0.f, 0.f, 0.f};
        #pragma unroll
        for (int ks = 0; ks < KS; ++ks) {
            half8 w = *(const half8*)(whdL + ((wv * KS + ks) * 64 + ln) * 8);
            half8 b = *(const half8*)(fb3 + (ks * 64 + ln) * 8);
            acc = __builtin_amdgcn_mfma_f32_16x16x32_f16(w, b, acc, 0, 0, 0);
        }
        if (lr < BT) {
            int o0 = wv * 16 + lb * 4;
            int obase = (b0 + lr) * (kT * kO) + (kT - 1) * kO;
            #pragma unroll
            for (int rg = 0; rg < 4; ++rg) {
                int o = o0 + rg;
                if (o < kO) out[obase + o] = sig_(acc[rg] + hb[o]);
            }
        }
    }

    // ---- final hidden states: stage in LDS (Gs) for coalesced global writes
    #pragma unroll
    for (int s = 0; s < 2; ++s) {
        int idx = tid + s * 1024;
        if (idx < BT * kH) {
            Gs[idx] = h1r[s];
            Gs[1600 + idx] = h2r[s];
            Gs[3200 + idx] = h3r[s];
        }
    }
    __syncthreads();
    for (int i = tid; i < BT * kH; i += 1024) {
        int n = i / kH, j = i - n * kH;
        int src = j * BT + n;
        out[OH1 + (b0 + n) * kH + j] = Gs[src];
        out[OH2 + (b0 + n) * kH + j] = Gs[1600 + src];
        out[OH3 + (b0 + n) * kH + j] = Gs[3200 + src];
    }
}

extern "C" void kernel_launch(void* const* d_in, const int* in_sizes, int n_in,
                              void* d_out, int out_size, void* d_ws, size_t ws_size,
                              hipStream_t stream) {
    (void)in_sizes; (void)n_in; (void)out_size; (void)ws_size;
    const float* enc  = (const float*)d_in[0];
    const float* h1in = (const float*)d_in[1];
    const float* h2in = (const float*)d_in[2];
    const float* h3in = (const float*)d_in[3];
    const float* bn_g = (const float*)d_in[4];
    const float* bn_b = (const float*)d_in[5];
    const float* bn_m = (const float*)d_in[6];
    const float* bn_v = (const float*)d_in[7];
    const float* fciW = (const float*)d_in[8];
    const float* fcib = (const float*)d_in[9];
    const float* Wih1 = (const float*)d_in[10];
    const float* Whh1 = (const float*)d_in[11];
    const float* bih1 = (const float*)d_in[12];
    const float* bhh1 = (const float*)d_in[13];
    const float* Wih2 = (const float*)d_in[14];
    const float* Whh2 = (const float*)d_in[15];
    const float* bih2 = (const float*)d_in[16];
    const float* bhh2 = (const float*)d_in[17];
    const float* Wih3 = (const float*)d_in[18];
    const float* Whh3 = (const float*)d_in[19];
    const float* bih3 = (const float*)d_in[20];
    const float* bhh3 = (const float*)d_in[21];
    const float* fcoW = (const float*)d_in[22];
    const float* fcob = (const float*)d_in[23];
    float* ws  = (float*)d_ws;
    float* out = (float*)d_out;

    hipLaunchKernelGGL(prep_transpose2, dim3(625), dim3(256), 0, stream, Wih1, fciW, ws);
    hipLaunchKernelGGL(prep_frags, dim3(340), dim3(256), 0, stream,
                       Whh1, Wih2, Whh2, Wih3, Whh3, fcoW, ws);
    hipLaunchKernelGGL(prep_input, dim3(kB), dim3(256), 0, stream,
                       enc, bn_g, bn_b, bn_m, bn_v, fcib, bih1, ws);
    hipLaunchKernelGGL(gru_main, dim3(NWG), dim3(1024), 0, stream,
                       ws, h1in, h2in, h3in, bhh1, bih2, bhh2, bih3, bhh3, fcob, out);
}